// Round 3
// baseline (1156.717 us; speedup 1.0000x reference)
//
#include <hip/hip_runtime.h>
#include <hip/hip_cooperative_groups.h>

namespace cg = cooperative_groups;

#define NN 12288
#define FF 128
#define HH 64
#define CC 16
#define CAP 128
#define NBLK 1024
#define NWAVE (NBLK * 4)   // 4096 waves; 12288 rows = exactly 3 rows/wave/phase

typedef float f32x4 __attribute__((ext_vector_type(4)));

// ===========================================================================
// Fused cooperative kernel: 1024 blocks x 256 threads = 4 blocks/CU exactly
// co-resident (LDS 38.9 KB/block -> 4/CU; launch_bounds(256,4) caps VGPR<=128).
//   phase 1: stream adj (604 MB) -> capped CSR + dinv. Wave-per-row,
//            wave-private compaction: NO atomics, NO shfl in the hot path
//            (`base` is wave-uniform: every lane adds popcll(ballot)).
//   phase 2: xp[i] = dinv_i * (x_i @ W1)        (W1 staged once in LDS)
//   phase 3: h1s[i] = dinv_i*relu(dinv_i*(xp_i + sum_nbr xp_j))  (256B gathers)
//   phase 4: out[i] = log_softmax(relu(dinv_i*(h1s_i + sum_nbr h1s_j) @ W2))
// grid.sync() between phases (device-scope fence -> cross-XCD visibility).
// ===========================================================================
__global__ __launch_bounds__(256, 4) void k_fused(
        const float* __restrict__ adj, const float* __restrict__ x,
        const float* __restrict__ W1,  const float* __restrict__ W2,
        int* __restrict__ cnt, float* __restrict__ dinv, int* __restrict__ nbr,
        float* __restrict__ xp, float* __restrict__ h1s, float* __restrict__ out)
{
    __shared__ float s_W1[FF * HH];   // 32 KB, live phases 2..4
    __shared__ float s_W2[HH * CC];   // 4 KB
    __shared__ float s_x[4][FF];      // 2 KB, per-wave scratch (phases 2,4)

    // stage weights once (consumed after the first __syncthreads in phase 2)
    for (int t = threadIdx.x; t < FF * HH / 4; t += 256)
        ((f32x4*)s_W1)[t] = ((const f32x4*)W1)[t];
    for (int t = threadIdx.x; t < HH * CC; t += 256) s_W2[t] = W2[t];

    const int wave = threadIdx.x >> 6;
    const int lane = threadIdx.x & 63;
    const int gw   = blockIdx.x * 4 + wave;        // global wave id 0..4095
    const unsigned long long lt = (lane == 63) ? (~0ull >> 1)
                                               : ((1ull << lane) - 1ull);

    // ---- phase 1: degree + capped neighbor list ---------------------------
    for (int r = gw; r < NN; r += NWAVE) {
        const f32x4* row = (const f32x4*)(adj + (size_t)r * NN);  // 3072 vec4
        int* my = nbr + (size_t)r * CAP;
        int base = 0;                               // wave-uniform running count
        #pragma unroll 4
        for (int it = 0; it < NN / 4 / 64; ++it) {  // 48 iters, 1 KB/wave each
            const int vi = it * 64 + lane;
            const f32x4 v = row[vi];
            #pragma unroll
            for (int q = 0; q < 4; ++q) {
                const unsigned long long m = __ballot(v[q] != 0.f);
                if (m) {                            // wave-uniform, ~12% taken
                    if (v[q] != 0.f) {
                        const int s = base + __popcll(m & lt);
                        if (s < CAP) my[s] = vi * 4 + q;
                    }
                    base += __popcll(m);
                }
            }
        }
        if (lane == 0) {
            cnt[r]  = min(base, CAP);
            dinv[r] = 1.0f / sqrtf((float)(base + 1));  // +1 = self loop
        }
    }
    cg::this_grid().sync();

    // ---- phase 2: project xp = dinv * (x @ W1) ----------------------------
    for (int r = gw; r < NN; r += NWAVE) {          // exactly 3 uniform iters
        const float2 xv = *(const float2*)(x + (size_t)r * FF + 2 * lane);
        s_x[wave][2 * lane]     = xv.x;
        s_x[wave][2 * lane + 1] = xv.y;
        __syncthreads();                            // also covers weight stage
        float h = 0.f;
        #pragma unroll 8
        for (int f = 0; f < FF; ++f) h += s_x[wave][f] * s_W1[f * HH + lane];
        xp[(size_t)r * HH + lane] = dinv[r] * h;
        __syncthreads();                            // s_x reuse next iter
    }
    cg::this_grid().sync();

    // ---- phase 3: layer-1 aggregation over 256B L2-resident xp rows -------
    for (int r = gw; r < NN; r += NWAVE) {
        const float di = dinv[r];
        float a = xp[(size_t)r * HH + lane];        // self (dinv_r-scaled)
        const int c = cnt[r];
        const int* nb = nbr + (size_t)r * CAP;
        int k = 0;
        for (; k + 4 <= c; k += 4) {                // 4 independent loads/wait
            const int4 j4 = *(const int4*)(nb + k);
            const float a0 = xp[(size_t)j4.x * HH + lane];
            const float a1 = xp[(size_t)j4.y * HH + lane];
            const float a2 = xp[(size_t)j4.z * HH + lane];
            const float a3 = xp[(size_t)j4.w * HH + lane];
            a += (a0 + a1) + (a2 + a3);
        }
        for (; k < c; ++k) a += xp[(size_t)nb[k] * HH + lane];
        h1s[(size_t)r * HH + lane] = di * fmaxf(di * a, 0.f);
    }
    cg::this_grid().sync();

    // ---- phase 4: layer-2 aggregation + 64x16 matvec + log_softmax --------
    for (int r = gw; r < NN; r += NWAVE) {
        float a = h1s[(size_t)r * HH + lane];       // self
        const int c = cnt[r];
        const int* nb = nbr + (size_t)r * CAP;
        int k = 0;
        for (; k + 4 <= c; k += 4) {
            const int4 j4 = *(const int4*)(nb + k);
            const float a0 = h1s[(size_t)j4.x * HH + lane];
            const float a1 = h1s[(size_t)j4.y * HH + lane];
            const float a2 = h1s[(size_t)j4.z * HH + lane];
            const float a3 = h1s[(size_t)j4.w * HH + lane];
            a += (a0 + a1) + (a2 + a3);
        }
        for (; k < c; ++k) a += h1s[(size_t)nb[k] * HH + lane];
        s_x[wave][lane] = a * dinv[r];              // reuse s_x as s_a[4][64+]
        __syncthreads();
        float h = 0.f;
        if (lane < CC) {
            #pragma unroll
            for (int o = 0; o < HH; ++o) h += s_x[wave][o] * s_W2[o * CC + lane];
            h = fmaxf(h, 0.f);
        }
        float m = h;
        for (int d = 8; d >= 1; d >>= 1) m = fmaxf(m, __shfl_xor(m, d, 16));
        const float e = expf(h - m);
        float s = e;
        for (int d = 8; d >= 1; d >>= 1) s += __shfl_xor(s, d, 16);
        if (lane < CC) out[(size_t)r * CC + lane] = (h - m) - logf(s);
        __syncthreads();                            // s_x reuse next iter
    }
}

// ===========================================================================
// Fallback path (R2 kernels, proven): used only if cooperative launch fails.
// ===========================================================================
__global__ __launch_bounds__(256) void k_build(const float* __restrict__ adj,
                                               int* __restrict__ cnt,
                                               float* __restrict__ dinv,
                                               int* __restrict__ nbr) {
    const int i = blockIdx.x;
    __shared__ int s_cnt;
    if (threadIdx.x == 0) s_cnt = 0;
    __syncthreads();
    const f32x4* row = (const f32x4*)(adj + (size_t)i * NN);
    int* my_nbr = nbr + (size_t)i * CAP;
    const int lane = threadIdx.x & 63;
    const unsigned long long lt_mask = (lane == 63) ? ~0ull >> 1
                                                    : (1ull << lane) - 1ull;
    #pragma unroll
    for (int it = 0; it < (NN / 4 / 256); ++it) {
        const int vi = it * 256 + threadIdx.x;
        const f32x4 v = row[vi];
        #pragma unroll
        for (int q = 0; q < 4; ++q) {
            const unsigned long long m = __ballot(v[q] != 0.f);
            if (m) {
                int base = 0;
                if (lane == __ffsll((long long)m) - 1)
                    base = atomicAdd(&s_cnt, __popcll(m));
                base = __shfl(base, __ffsll((long long)m) - 1);
                if (v[q] != 0.f) {
                    const int s = base + __popcll(m & lt_mask);
                    if (s < CAP) my_nbr[s] = vi * 4 + q;
                }
            }
        }
    }
    __syncthreads();
    if (threadIdx.x == 0) {
        cnt[i] = min(s_cnt, CAP);
        dinv[i] = 1.0f / sqrtf((float)(s_cnt + 1));
    }
}

__global__ __launch_bounds__(512) void k_proj(const float* __restrict__ W1,
                                              const float* __restrict__ dinv,
                                              const float* __restrict__ x,
                                              float* __restrict__ xp) {
    __shared__ float s_W1[FF * HH];
    __shared__ float s_x[8][FF];
    {
        const f32x4* Wv = (const f32x4*)W1;
        f32x4* Sv = (f32x4*)s_W1;
        for (int t = threadIdx.x; t < FF * HH / 4; t += 512) Sv[t] = Wv[t];
    }
    const int wave = threadIdx.x >> 6;
    const int lane = threadIdx.x & 63;
    const int i = blockIdx.x * 8 + wave;
    const float2 xv = *(const float2*)(x + (size_t)i * FF + 2 * lane);
    s_x[wave][2 * lane]     = xv.x;
    s_x[wave][2 * lane + 1] = xv.y;
    __syncthreads();
    float h = 0.f;
    #pragma unroll 8
    for (int f = 0; f < FF; ++f) h += s_x[wave][f] * s_W1[f * HH + lane];
    xp[(size_t)i * HH + lane] = dinv[i] * h;
}

__global__ __launch_bounds__(512) void k_agg1(const int* __restrict__ cnt,
                                              const float* __restrict__ dinv,
                                              const int* __restrict__ nbr,
                                              const float* __restrict__ xp,
                                              float* __restrict__ h1s) {
    const int wave = threadIdx.x >> 6;
    const int lane = threadIdx.x & 63;
    const int i = blockIdx.x * 8 + wave;
    const float di = dinv[i];
    float a = xp[(size_t)i * HH + lane];
    const int c = cnt[i];
    const int* nb = nbr + (size_t)i * CAP;
    int k = 0;
    for (; k + 4 <= c; k += 4) {
        const int4 j4 = *(const int4*)(nb + k);
        const float a0 = xp[(size_t)j4.x * HH + lane];
        const float a1 = xp[(size_t)j4.y * HH + lane];
        const float a2 = xp[(size_t)j4.z * HH + lane];
        const float a3 = xp[(size_t)j4.w * HH + lane];
        a += (a0 + a1) + (a2 + a3);
    }
    for (; k < c; ++k) a += xp[(size_t)nb[k] * HH + lane];
    h1s[(size_t)i * HH + lane] = di * fmaxf(di * a, 0.f);
}

__global__ __launch_bounds__(512) void k_layer2(const float* __restrict__ W2,
                                                const int* __restrict__ cnt,
                                                const float* __restrict__ dinv,
                                                const int* __restrict__ nbr,
                                                const float* __restrict__ h1s,
                                                float* __restrict__ out) {
    __shared__ float s_W2[HH * CC];
    __shared__ float s_a[8][HH];
    for (int t = threadIdx.x; t < HH * CC; t += 512) s_W2[t] = W2[t];
    __syncthreads();
    const int wave = threadIdx.x >> 6;
    const int lane = threadIdx.x & 63;
    const int i = blockIdx.x * 8 + wave;
    float a = h1s[(size_t)i * HH + lane];
    const int c = cnt[i];
    const int* nb = nbr + (size_t)i * CAP;
    int k = 0;
    for (; k + 4 <= c; k += 4) {
        const int4 j4 = *(const int4*)(nb + k);
        const float a0 = h1s[(size_t)j4.x * HH + lane];
        const float a1 = h1s[(size_t)j4.y * HH + lane];
        const float a2 = h1s[(size_t)j4.z * HH + lane];
        const float a3 = h1s[(size_t)j4.w * HH + lane];
        a += (a0 + a1) + (a2 + a3);
    }
    for (; k < c; ++k) a += h1s[(size_t)nb[k] * HH + lane];
    s_a[wave][lane] = a * dinv[i];
    __syncthreads();
    float h = 0.f;
    if (lane < CC) {
        #pragma unroll
        for (int o = 0; o < HH; ++o) h += s_a[wave][o] * s_W2[o * CC + lane];
        h = fmaxf(h, 0.f);
    }
    float m = h;
    for (int d = 8; d >= 1; d >>= 1) m = fmaxf(m, __shfl_xor(m, d, 16));
    const float e = expf(h - m);
    float s = e;
    for (int d = 8; d >= 1; d >>= 1) s += __shfl_xor(s, d, 16);
    const float r = (h - m) - logf(s);
    if (lane < CC) out[(size_t)i * CC + lane] = r;
}

// ---------------------------------------------------------------------------
// Workspace: cnt[NN] int | dinv[NN] f32 | nbr[NN*CAP] int | xp[NN*HH] f32 |
//            h1s[NN*HH] f32  — ~12.6 MB, all written before read each launch.
// ---------------------------------------------------------------------------
extern "C" void kernel_launch(void* const* d_in, const int* in_sizes, int n_in,
                              void* d_out, int out_size, void* d_ws, size_t ws_size,
                              hipStream_t stream) {
    const float* x   = (const float*)d_in[0];
    const float* adj = (const float*)d_in[1];
    const float* W1  = (const float*)d_in[2];
    const float* W2  = (const float*)d_in[3];
    float* out = (float*)d_out;

    char* p = (char*)d_ws;
    int*   cnt  = (int*)p;    p += (size_t)NN * sizeof(int);
    float* dinv = (float*)p;  p += (size_t)NN * sizeof(float);
    int*   nbr  = (int*)p;    p += (size_t)NN * CAP * sizeof(int);
    float* xp   = (float*)p;  p += (size_t)NN * HH * sizeof(float);
    float* h1s  = (float*)p;

    void* args[] = {(void*)&adj, (void*)&x, (void*)&W1, (void*)&W2,
                    (void*)&cnt, (void*)&dinv, (void*)&nbr,
                    (void*)&xp, (void*)&h1s, (void*)&out};
    hipError_t e = hipLaunchCooperativeKernel((const void*)k_fused,
                                              dim3(NBLK), dim3(256),
                                              args, 0, stream);
    if (e != hipSuccess) {  // fallback: proven 4-kernel path
        k_build<<<NN, 256, 0, stream>>>(adj, cnt, dinv, nbr);
        k_proj<<<NN / 8, 512, 0, stream>>>(W1, dinv, x, xp);
        k_agg1<<<NN / 8, 512, 0, stream>>>(cnt, dinv, nbr, xp, h1s);
        k_layer2<<<NN / 8, 512, 0, stream>>>(W2, cnt, dinv, nbr, h1s, out);
    }
}

// Round 4
// 817.208 us; speedup vs baseline: 1.4154x; 1.4154x over previous
//
#include <hip/hip_runtime.h>

#define NN 12288
#define FF 128
#define HH 64
#define CC 16
#define CAP 128

#define NBLD 2048                  // build blocks (8/CU, no LDS -> 32 waves/CU)
#define NTHR (NBLD * 256)          // 524288 threads
#define NV4  (NN * (NN / 4))       // 37,748,736 vec4 in adj
#define NIT  (NV4 / NTHR)          // 72 iterations exactly (no remainder)

typedef float f32x4 __attribute__((ext_vector_type(4)));

// ---------------------------------------------------------------------------
// Build kernel, v2: GLOBAL-SEQUENTIAL sweep of adj (the D2D-copy pattern).
// At step t the whole grid reads one contiguous 8 MB window; windows sweep
// forward -> DRAM row-buffer/channel locality like a fill/copy kernel, unlike
// R0-R3's per-row private streams (measured: 555us, 617 GB/s, VALUBusy 4%).
// A wave's 64 lanes = one aligned 1 KB chunk; 48 KB rows = 48 chunks exactly,
// so `row` is wave-uniform and ballot compaction works unchanged. Slot base
// comes from a global atomicAdd on cnt[row] (~270K atomics over 12K addrs).
// Neighbor order within a row becomes arbitrary (only changes fp32 sum order).
// One-deep prefetch keeps a load in flight through the ballot/compaction code.
// ---------------------------------------------------------------------------
__global__ __launch_bounds__(256) void k_build2(const float* __restrict__ adj,
                                                int* __restrict__ cnt,
                                                int* __restrict__ nbr) {
    const int lane = threadIdx.x & 63;
    const unsigned long long lt = (lane == 63) ? (~0ull >> 1)
                                               : ((1ull << lane) - 1ull);
    const f32x4* av = (const f32x4*)adj;

    unsigned vi = blockIdx.x * 256 + threadIdx.x;   // vec4 index, stride NTHR
    f32x4 cur = av[vi];
    for (int t = 0; t < NIT; ++t) {
        const unsigned vnext = vi + NTHR;
        f32x4 nxt = {};
        if (t + 1 < NIT) nxt = av[vnext];           // prefetch next window
        const unsigned row  = vi / 3072u;           // wave-uniform (magic mul)
        const unsigned colv = vi - row * 3072u;
        #pragma unroll
        for (int q = 0; q < 4; ++q) {
            const unsigned long long m = __ballot(cur[q] != 0.f);
            if (m) {                                // wave-uniform branch
                const int lead = __ffsll((long long)m) - 1;
                int base = 0;
                if (lane == lead) base = atomicAdd(&cnt[row], __popcll(m));
                base = __shfl(base, lead);
                if (cur[q] != 0.f) {
                    const int s = base + __popcll(m & lt);
                    if (s < CAP) nbr[(size_t)row * CAP + s] = colv * 4 + q;
                }
            }
        }
        cur = nxt;
        vi  = vnext;
    }
}

// ---------------------------------------------------------------------------
// k_proj: xp[i,:] = dinv_i * (x_i @ W1)   [64]   ((Ax)W1 == A(xW1))
// dinv computed on the fly from cnt (exact: 1/sqrt, not rsqrt approx).
// ---------------------------------------------------------------------------
__global__ __launch_bounds__(512) void k_proj(const float* __restrict__ W1,
                                              const int* __restrict__ cnt,
                                              const float* __restrict__ x,
                                              float* __restrict__ xp) {
    __shared__ float s_W1[FF * HH];   // 32 KB
    __shared__ float s_x[8][FF];      // 4 KB
    {
        const f32x4* Wv = (const f32x4*)W1;
        f32x4* Sv = (f32x4*)s_W1;
        for (int t = threadIdx.x; t < FF * HH / 4; t += 512) Sv[t] = Wv[t];
    }
    const int wave = threadIdx.x >> 6;
    const int lane = threadIdx.x & 63;
    const int i = blockIdx.x * 8 + wave;

    const float2 xv = *(const float2*)(x + (size_t)i * FF + 2 * lane);
    s_x[wave][2 * lane]     = xv.x;
    s_x[wave][2 * lane + 1] = xv.y;
    __syncthreads();
    float h = 0.f;
    #pragma unroll 8
    for (int f = 0; f < FF; ++f) h += s_x[wave][f] * s_W1[f * HH + lane];
    const float di = 1.0f / sqrtf((float)(cnt[i] + 1));   // +1 = self loop
    xp[(size_t)i * HH + lane] = di * h;
}

// ---------------------------------------------------------------------------
// k_agg1: h1s[i,:] = dinv_i * relu(dinv_i * (xp_i + sum_nbr xp_j))
// (trailing dinv_i pre-folds layer-2's left D^-1/2). 256B L2-resident gathers,
// int4 neighbor fetch -> 4 independent loads per wait. No LDS.
// ---------------------------------------------------------------------------
__global__ __launch_bounds__(512) void k_agg1(const int* __restrict__ cnt,
                                              const int* __restrict__ nbr,
                                              const float* __restrict__ xp,
                                              float* __restrict__ h1s) {
    const int wave = threadIdx.x >> 6;
    const int lane = threadIdx.x & 63;
    const int i = blockIdx.x * 8 + wave;

    const int c = min(cnt[i], CAP);
    const float di = 1.0f / sqrtf((float)(cnt[i] + 1));
    float a = xp[(size_t)i * HH + lane];  // self (already dinv_i-scaled)
    const int* nb = nbr + (size_t)i * CAP;

    int k = 0;
    for (; k + 4 <= c; k += 4) {
        const int4 j4 = *(const int4*)(nb + k);   // 16B-aligned (CAP*4 stride)
        const float a0 = xp[(size_t)j4.x * HH + lane];
        const float a1 = xp[(size_t)j4.y * HH + lane];
        const float a2 = xp[(size_t)j4.z * HH + lane];
        const float a3 = xp[(size_t)j4.w * HH + lane];
        a += (a0 + a1) + (a2 + a3);
    }
    for (; k < c; ++k) a += xp[(size_t)nb[k] * HH + lane];

    h1s[(size_t)i * HH + lane] = di * fmaxf(di * a, 0.f);
}

// ---------------------------------------------------------------------------
// k_layer2: agg2 = dinv_i*(h1s_i + sum_nbr h1s_j); out = log_softmax(relu(agg2@W2))
// ---------------------------------------------------------------------------
__global__ __launch_bounds__(512) void k_layer2(const float* __restrict__ W2,
                                                const int* __restrict__ cnt,
                                                const int* __restrict__ nbr,
                                                const float* __restrict__ h1s,
                                                float* __restrict__ out) {
    __shared__ float s_W2[HH * CC];   // 4 KB
    __shared__ float s_a[8][HH];      // 2 KB
    for (int t = threadIdx.x; t < HH * CC; t += 512) s_W2[t] = W2[t];
    __syncthreads();

    const int wave = threadIdx.x >> 6;
    const int lane = threadIdx.x & 63;
    const int i = blockIdx.x * 8 + wave;

    const int c = min(cnt[i], CAP);
    float a = h1s[(size_t)i * HH + lane];  // self
    const int* nb = nbr + (size_t)i * CAP;

    int k = 0;
    for (; k + 4 <= c; k += 4) {
        const int4 j4 = *(const int4*)(nb + k);
        const float a0 = h1s[(size_t)j4.x * HH + lane];
        const float a1 = h1s[(size_t)j4.y * HH + lane];
        const float a2 = h1s[(size_t)j4.z * HH + lane];
        const float a3 = h1s[(size_t)j4.w * HH + lane];
        a += (a0 + a1) + (a2 + a3);
    }
    for (; k < c; ++k) a += h1s[(size_t)nb[k] * HH + lane];
    s_a[wave][lane] = a * (1.0f / sqrtf((float)(cnt[i] + 1)));
    __syncthreads();

    float h = 0.f;
    if (lane < CC) {
        #pragma unroll
        for (int o = 0; o < HH; ++o) h += s_a[wave][o] * s_W2[o * CC + lane];
        h = fmaxf(h, 0.f);
    }
    // log_softmax across 16-lane groups (lanes>=16 compute on h=0, never stored)
    float m = h;
    for (int d = 8; d >= 1; d >>= 1) m = fmaxf(m, __shfl_xor(m, d, 16));
    const float e = expf(h - m);
    float s = e;
    for (int d = 8; d >= 1; d >>= 1) s += __shfl_xor(s, d, 16);
    const float r = (h - m) - logf(s);
    if (lane < CC) out[(size_t)i * CC + lane] = r;
}

// ---------------------------------------------------------------------------
// Workspace: cnt[NN] int | nbr[NN*CAP] int | xp[NN*HH] f32 | h1s[NN*HH] f32
// ~12.5 MB. cnt must be zeroed before the atomic build (hipMemsetAsync is
// graph-capture-safe; the harness itself uses it for poisoning).
// ---------------------------------------------------------------------------
extern "C" void kernel_launch(void* const* d_in, const int* in_sizes, int n_in,
                              void* d_out, int out_size, void* d_ws, size_t ws_size,
                              hipStream_t stream) {
    const float* x   = (const float*)d_in[0];
    const float* adj = (const float*)d_in[1];
    const float* W1  = (const float*)d_in[2];
    const float* W2  = (const float*)d_in[3];
    float* out = (float*)d_out;

    char* p = (char*)d_ws;
    int*   cnt = (int*)p;    p += (size_t)NN * sizeof(int);
    int*   nbr = (int*)p;    p += (size_t)NN * CAP * sizeof(int);
    float* xp  = (float*)p;  p += (size_t)NN * HH * sizeof(float);
    float* h1s = (float*)p;

    hipMemsetAsync(cnt, 0, (size_t)NN * sizeof(int), stream);
    k_build2<<<NBLD, 256, 0, stream>>>(adj, cnt, nbr);
    k_proj<<<NN / 8, 512, 0, stream>>>(W1, cnt, x, xp);
    k_agg1<<<NN / 8, 512, 0, stream>>>(cnt, nbr, xp, h1s);
    k_layer2<<<NN / 8, 512, 0, stream>>>(W2, cnt, nbr, h1s, out);
}

// Round 5
// 792.677 us; speedup vs baseline: 1.4593x; 1.0309x over previous
//
#include <hip/hip_runtime.h>

#define NN 12288
#define FF 128
#define HH 64
#define CC 16
#define CAP 128

#define NBLD 2048                  // scan blocks (8/CU, no LDS -> 32 waves/CU)
#define NTHR (NBLD * 256)          // 524288 threads
#define NV4  (NN * (NN / 4))       // 37,748,736 vec4 in adj
#define NIT  (NV4 / NTHR)          // 72 iterations exactly (no remainder)
#define NWORDS (NV4 / 16)          // bitmap u64 words: 2,359,296 (18.9 MB)

typedef float f32x4 __attribute__((ext_vector_type(4)));
typedef unsigned long long u64;

// ---------------------------------------------------------------------------
// Pass 1 (k_scan): BRANCH-FREE streaming scan of adj -> nonzero bitmask.
// The R0-R4 builds all interleaved ballot/branch/atomic/compact-store logic
// into the 604 MB read stream and all stuck at ~1.6 TB/s effective. This pass
// is shaped like the 6.4 TB/s fill kernel: grid-stride sweep, 16B/lane NT
// loads, NO data-dependent control flow, 2-deep prefetch; per 1 KB wave-chunk
// the only output is one coalesced 32 B store (lanes 0..3) of 4 ballot masks.
// Bitmap encoding (permuted by the lane interleave): for 256-value chunk cc,
// word q (=0..3) bit k  <->  column cc*256 + 4k + q.
// Traffic: 604 MB read + 18.9 MB write ~= 104 us at copy BW.
// ---------------------------------------------------------------------------
__global__ __launch_bounds__(256) void k_scan(const float* __restrict__ adj,
                                              u64* __restrict__ bmp) {
    const int lane = threadIdx.x & 63;
    const f32x4* av = (const f32x4*)adj;

    unsigned vi = blockIdx.x * 256 + threadIdx.x;   // vec4 index, stride NTHR
    f32x4 c0 = __builtin_nontemporal_load(av + vi);
    f32x4 c1 = __builtin_nontemporal_load(av + vi + NTHR);
    for (int t = 0; t < NIT; ++t) {
        f32x4 c2 = {};
        if (t + 2 < NIT) c2 = __builtin_nontemporal_load(av + vi + 2 * NTHR);
        const u64 m0 = __ballot(c0[0] != 0.f);
        const u64 m1 = __ballot(c0[1] != 0.f);
        const u64 m2 = __ballot(c0[2] != 0.f);
        const u64 m3 = __ballot(c0[3] != 0.f);
        // wave's first vec4 idx: vi&~63 -> bitmap word base (wv0*4)/64
        const u64 v = (lane == 0) ? m0 : (lane == 1) ? m1
                    : (lane == 2) ? m2 : m3;
        if (lane < 4) bmp[((vi & ~63u) >> 4) + lane] = v;  // one 32B txn/wave
        c0 = c1; c1 = c2; vi += NTHR;
    }
}

// ---------------------------------------------------------------------------
// Pass 2 (k_compact): branchy compaction over the 18.9 MB L2/LLC-resident
// bitmap (NOT the 604 MB stream). Wave per row: 192 words, 3 coalesced u64
// loads/lane; popcount + wave prefix-scan gives deterministic slot bases (no
// atomics anywhere); each lane serially expands its ~0.4 expected bits.
// Neighbor order is lane-major (arbitrary) — only changes fp32 sum order.
// ---------------------------------------------------------------------------
__global__ __launch_bounds__(256) void k_compact(const u64* __restrict__ bmp,
                                                 int* __restrict__ cnt,
                                                 int* __restrict__ nbr) {
    const int wave = threadIdx.x >> 6;
    const int lane = threadIdx.x & 63;
    const int row  = blockIdx.x * 4 + wave;

    const u64* rw = bmp + (size_t)row * 192;   // 12288 cols = 48 chunks * 4
    const u64 w0 = rw[lane];
    const u64 w1 = rw[lane + 64];
    const u64 w2 = rw[lane + 128];
    const int c = __popcll(w0) + __popcll(w1) + __popcll(w2);

    int incl = c;                               // wave inclusive prefix scan
    #pragma unroll
    for (int d = 1; d < 64; d <<= 1) {
        const int n = __shfl_up(incl, d);
        if (lane >= d) incl += n;
    }
    const int total = __shfl(incl, 63);
    int base = incl - c;                        // exclusive base for this lane

    int* my = nbr + (size_t)row * CAP;
    #pragma unroll
    for (int j = 0; j < 3; ++j) {
        u64 w = (j == 0) ? w0 : (j == 1) ? w1 : w2;
        const int widx = lane + 64 * j;
        const int cc = widx >> 2, q = widx & 3; // word -> (chunk, phase)
        while (w) {
            const int k = __ffsll((long long)w) - 1;
            if (base < CAP) my[base] = (cc << 8) + (k << 2) + q;
            ++base;
            w &= w - 1;
        }
    }
    if (lane == 0) cnt[row] = total;            // true degree (uncapped)
}

// ---------------------------------------------------------------------------
// k_proj: xp[i,:] = dinv_i * (x_i @ W1)   [64]   ((Ax)W1 == A(xW1))
// ---------------------------------------------------------------------------
__global__ __launch_bounds__(512) void k_proj(const float* __restrict__ W1,
                                              const int* __restrict__ cnt,
                                              const float* __restrict__ x,
                                              float* __restrict__ xp) {
    __shared__ float s_W1[FF * HH];   // 32 KB
    __shared__ float s_x[8][FF];      // 4 KB
    {
        const f32x4* Wv = (const f32x4*)W1;
        f32x4* Sv = (f32x4*)s_W1;
        for (int t = threadIdx.x; t < FF * HH / 4; t += 512) Sv[t] = Wv[t];
    }
    const int wave = threadIdx.x >> 6;
    const int lane = threadIdx.x & 63;
    const int i = blockIdx.x * 8 + wave;

    const float2 xv = *(const float2*)(x + (size_t)i * FF + 2 * lane);
    s_x[wave][2 * lane]     = xv.x;
    s_x[wave][2 * lane + 1] = xv.y;
    __syncthreads();
    float h = 0.f;
    #pragma unroll 8
    for (int f = 0; f < FF; ++f) h += s_x[wave][f] * s_W1[f * HH + lane];
    const float di = 1.0f / sqrtf((float)(cnt[i] + 1));   // +1 = self loop
    xp[(size_t)i * HH + lane] = di * h;
}

// ---------------------------------------------------------------------------
// k_agg1: h1s[i,:] = dinv_i * relu(dinv_i * (xp_i + sum_nbr xp_j))
// (trailing dinv_i pre-folds layer-2's left D^-1/2). 256B L2-resident gathers,
// int4 neighbor fetch -> 4 independent loads per wait. No LDS.
// ---------------------------------------------------------------------------
__global__ __launch_bounds__(512) void k_agg1(const int* __restrict__ cnt,
                                              const int* __restrict__ nbr,
                                              const float* __restrict__ xp,
                                              float* __restrict__ h1s) {
    const int wave = threadIdx.x >> 6;
    const int lane = threadIdx.x & 63;
    const int i = blockIdx.x * 8 + wave;

    const int c = min(cnt[i], CAP);
    const float di = 1.0f / sqrtf((float)(cnt[i] + 1));
    float a = xp[(size_t)i * HH + lane];  // self (already dinv_i-scaled)
    const int* nb = nbr + (size_t)i * CAP;

    int k = 0;
    for (; k + 4 <= c; k += 4) {
        const int4 j4 = *(const int4*)(nb + k);   // 16B-aligned (CAP*4 stride)
        const float a0 = xp[(size_t)j4.x * HH + lane];
        const float a1 = xp[(size_t)j4.y * HH + lane];
        const float a2 = xp[(size_t)j4.z * HH + lane];
        const float a3 = xp[(size_t)j4.w * HH + lane];
        a += (a0 + a1) + (a2 + a3);
    }
    for (; k < c; ++k) a += xp[(size_t)nb[k] * HH + lane];

    h1s[(size_t)i * HH + lane] = di * fmaxf(di * a, 0.f);
}

// ---------------------------------------------------------------------------
// k_layer2: agg2 = dinv_i*(h1s_i + sum_nbr h1s_j); out = log_softmax(relu(agg2@W2))
// ---------------------------------------------------------------------------
__global__ __launch_bounds__(512) void k_layer2(const float* __restrict__ W2,
                                                const int* __restrict__ cnt,
                                                const int* __restrict__ nbr,
                                                const float* __restrict__ h1s,
                                                float* __restrict__ out) {
    __shared__ float s_W2[HH * CC];   // 4 KB
    __shared__ float s_a[8][HH];      // 2 KB
    for (int t = threadIdx.x; t < HH * CC; t += 512) s_W2[t] = W2[t];
    __syncthreads();

    const int wave = threadIdx.x >> 6;
    const int lane = threadIdx.x & 63;
    const int i = blockIdx.x * 8 + wave;

    const int c = min(cnt[i], CAP);
    float a = h1s[(size_t)i * HH + lane];  // self
    const int* nb = nbr + (size_t)i * CAP;

    int k = 0;
    for (; k + 4 <= c; k += 4) {
        const int4 j4 = *(const int4*)(nb + k);
        const float a0 = h1s[(size_t)j4.x * HH + lane];
        const float a1 = h1s[(size_t)j4.y * HH + lane];
        const float a2 = h1s[(size_t)j4.z * HH + lane];
        const float a3 = h1s[(size_t)j4.w * HH + lane];
        a += (a0 + a1) + (a2 + a3);
    }
    for (; k < c; ++k) a += h1s[(size_t)nb[k] * HH + lane];
    s_a[wave][lane] = a * (1.0f / sqrtf((float)(cnt[i] + 1)));
    __syncthreads();

    float h = 0.f;
    if (lane < CC) {
        #pragma unroll
        for (int o = 0; o < HH; ++o) h += s_a[wave][o] * s_W2[o * CC + lane];
        h = fmaxf(h, 0.f);
    }
    // log_softmax across 16-lane groups (lanes>=16 compute on h=0, never stored)
    float m = h;
    for (int d = 8; d >= 1; d >>= 1) m = fmaxf(m, __shfl_xor(m, d, 16));
    const float e = expf(h - m);
    float s = e;
    for (int d = 8; d >= 1; d >>= 1) s += __shfl_xor(s, d, 16);
    const float r = (h - m) - logf(s);
    if (lane < CC) out[(size_t)i * CC + lane] = r;
}

// ---------------------------------------------------------------------------
// Workspace: cnt[NN] int | nbr[NN*CAP] int | bmp[NWORDS] u64 (18.9 MB) |
//            xp[NN*HH] f32 | h1s[NN*HH] f32   — ~31.5 MB total.
// No memset needed: k_compact writes cnt unconditionally (no atomics).
// ---------------------------------------------------------------------------
extern "C" void kernel_launch(void* const* d_in, const int* in_sizes, int n_in,
                              void* d_out, int out_size, void* d_ws, size_t ws_size,
                              hipStream_t stream) {
    const float* x   = (const float*)d_in[0];
    const float* adj = (const float*)d_in[1];
    const float* W1  = (const float*)d_in[2];
    const float* W2  = (const float*)d_in[3];
    float* out = (float*)d_out;

    char* p = (char*)d_ws;
    int*   cnt = (int*)p;    p += (size_t)NN * sizeof(int);
    int*   nbr = (int*)p;    p += (size_t)NN * CAP * sizeof(int);
    u64*   bmp = (u64*)p;    p += (size_t)NWORDS * sizeof(u64);
    float* xp  = (float*)p;  p += (size_t)NN * HH * sizeof(float);
    float* h1s = (float*)p;

    k_scan<<<NBLD, 256, 0, stream>>>(adj, bmp);
    k_compact<<<NN / 4, 256, 0, stream>>>(bmp, cnt, nbr);
    k_proj<<<NN / 8, 512, 0, stream>>>(W1, cnt, x, xp);
    k_agg1<<<NN / 8, 512, 0, stream>>>(cnt, nbr, xp, h1s);
    k_layer2<<<NN / 8, 512, 0, stream>>>(W2, cnt, nbr, h1s, out);
}